// Round 13
// baseline (119.803 us; speedup 1.0000x reference)
//
#include <hip/hip_runtime.h>
#include <math.h>

// Problem constants
#define B_  8
#define D_  128
#define L_  2048
#define H_  8
#define DH_ 16

#define LOG2E 1.4426950408889634f

typedef __bf16 bf16x8 __attribute__((ext_vector_type(8)));
typedef float  floatx4 __attribute__((ext_vector_type(4)));
typedef float  floatx16 __attribute__((ext_vector_type(16)));

#if __has_builtin(__builtin_amdgcn_exp2f)
#define EXP2(x) __builtin_amdgcn_exp2f(x)
#else
#define EXP2(x) exp2f(x)
#endif

// ---------------------------------------------------------------------------
// Weight pre-convert (unchanged): fp32 W -> bf16 MFMA frag layout (lane idx =
// col, k = quad*8+j). tiles 0..7 = Q heads (W_q pre-scaled by DH^-0.5*log2e),
// 8..15 = K, 16..23 = V.
// ---------------------------------------------------------------------------
__global__ __launch_bounds__(256) void wconv_kernel(
    const float* __restrict__ wmem, const float* __restrict__ wq,
    __bf16* __restrict__ Wb) {
  const int tile = blockIdx.x;
  const int tid = threadIdx.x;
  const int kc = tid >> 6, lane = tid & 63;
  const int quad = lane >> 4, col = lane & 15;
  const float* src;
  float scale = 1.0f;
  if (tile < 8) {
    src = wq + (tile * 16 + col) * D_;
    scale = 0.25f * LOG2E;  // DH^-0.5 and log2e folded into W_q
  } else if (tile < 16) {
    src = wmem + ((tile - 8) * 16 + col) * D_;
  } else {
    src = wmem + (128 + (tile - 16) * 16 + col) * D_;
  }
  const float* p = src + kc * 32 + quad * 8;
  bf16x8 w;
#pragma unroll
  for (int j = 0; j < 8; ++j) w[j] = (__bf16)(p[j] * scale);
  *(bf16x8*)(Wb + ((size_t)((tile * 4 + kc) * 64) + lane) * 8) = w;
}

// ---------------------------------------------------------------------------
// Projection v3: SAME round-10 output layouts, but C-tiles are staged in LDS
// and dumped with coalesced 16B/lane stores (the old path did ~24 scattered
// 2-byte global stores per thread — the suspected fixed ~66us gap).
//   Qs [B,H,L,DH] natural.
//   Ks [B,H,L,DH], rows tau-permuted (key bits 2<->3 swapped): Ks[tau(l)]=K[l].
//   Vp [bh][tile=l>>5][row=dh 0..16][kk=l&31]; rows 0-15 = V^T*mask,
//      row 16 = mask (l-sum row), rows 17-31 unwritten (harmless garbage).
// grid = B*(L/16) = 1024 blocks x 256 threads.
// ---------------------------------------------------------------------------
__global__ __launch_bounds__(256) void proj_kernel(
    const float* __restrict__ qin, const int* __restrict__ mask,
    const __bf16* __restrict__ Wb, __bf16* __restrict__ Qs,
    __bf16* __restrict__ Ks, __bf16* __restrict__ Vp) {
  __shared__ float xl[16][132];        // row stride >= 128 (D)!
  __shared__ __bf16 qbuf[8][16][16];   // [head][l][dh]
  __shared__ __bf16 kbuf[8][16][16];   // [head][tau-row][dh]
  __shared__ __bf16 vbuf[8][17][16];   // [head][dh-row (16=mask)][key-in-16]
  const int b = blockIdx.x >> 7;
  const int l0 = (blockIdx.x & 127) * 16;
  const int tid = threadIdx.x;

  // Stage x tile [D][16l] -> LDS [16l][D]; 2 float4 loads/thread.
#pragma unroll
  for (int i = 0; i < 2; ++i) {
    int idx = i * 256 + tid;
    int d = idx >> 2;
    int l4 = (idx & 3) * 4;
    const float4 v = *(const float4*)&qin[(b * D_ + d) * L_ + l0 + l4];
    xl[l4 + 0][d] = v.x;
    xl[l4 + 1][d] = v.y;
    xl[l4 + 2][d] = v.z;
    xl[l4 + 3][d] = v.w;
  }
  // Mask -> vbuf row 16 for all 8 heads.
  if (tid < 128) {
    const int hh = tid >> 4, c = tid & 15;
    vbuf[hh][16][c] = (__bf16)(float)mask[b * L_ + l0 + c];
  }
  __syncthreads();

  const int lane = tid & 63, wave = tid >> 6;
  const int quad = lane >> 4, col = lane & 15;

  // x frags: rows 0..15 (idx = col), K=128. A for Q/K, B for V (swapped).
  bf16x8 af[4];
#pragma unroll
  for (int kc = 0; kc < 4; ++kc) {
    const float* s = &xl[col][kc * 32 + quad * 8];
#pragma unroll
    for (int j = 0; j < 8; ++j) af[kc][j] = (__bf16)s[j];
  }

  const int quadK = ((quad & 1) << 1) | (quad >> 1);   // tau: swap bits 2,3
  const float mvv = (float)mask[b * L_ + l0 + col];    // V column mask

#pragma unroll
  for (int tt = 0; tt < 6; ++tt) {
    const int tile = wave * 6 + tt;
    floatx4 acc = {0.f, 0.f, 0.f, 0.f};
    const bool isV = (tile >= 16);
#pragma unroll
    for (int kc = 0; kc < 4; ++kc) {
      bf16x8 wf =
          *(const bf16x8*)(Wb + ((size_t)((tile * 4 + kc) * 64) + lane) * 8);
      acc = isV ? __builtin_amdgcn_mfma_f32_16x16x32_bf16(wf, af[kc], acc, 0, 0, 0)
                : __builtin_amdgcn_mfma_f32_16x16x32_bf16(af[kc], wf, acc, 0, 0, 0);
    }
    if (tile < 8) {  // Q head: C row = l = quad*4+r, col = dh
#pragma unroll
      for (int r = 0; r < 4; ++r) qbuf[tile][quad * 4 + r][col] = (__bf16)acc[r];
    } else if (tile < 16) {  // K head: stage at tau-permuted row
#pragma unroll
      for (int r = 0; r < 4; ++r)
        kbuf[tile - 8][quadK * 4 + r][col] = (__bf16)acc[r];
    } else {  // V (swapped gemm): C row = dh = quad*4+r, col = key-in-16
#pragma unroll
      for (int r = 0; r < 4; ++r)
        vbuf[tile - 16][quad * 4 + r][col] = (__bf16)(acc[r] * mvv);
    }
  }
  __syncthreads();

  // ---- coalesced dump ----
  // Q & K: per head a 512B contiguous global chunk; 32 threads/head x 16B.
  {
    const int h = tid >> 5, sub = tid & 31;
    const size_t base = ((size_t)(b * H_ + h) * L_ + l0) * DH_;
    bf16x8 q8 = *(const bf16x8*)&qbuf[h][sub >> 1][(sub & 1) * 8];
    *(bf16x8*)(Qs + base + sub * 8) = q8;
    bf16x8 k8 = *(const bf16x8*)&kbuf[h][sub >> 1][(sub & 1) * 8];
    *(bf16x8*)(Ks + base + sub * 8) = k8;
  }
  // V: 8 heads x 17 rows, 32B contiguous each (2 x 16B stores per thread).
  if (tid < 136) {
    const int h = tid / 17, row = tid - h * 17;
    const size_t off =
        ((size_t)((b * H_ + h) * 64 + (l0 >> 5)) * 32 + row) * 32 + (l0 & 16);
    bf16x8 a = *(const bf16x8*)&vbuf[h][row][0];
    bf16x8 c = *(const bf16x8*)&vbuf[h][row][8];
    *(bf16x8*)(Vp + off) = a;
    *(bf16x8*)(Vp + off + 8) = c;
  }
}

// ---------------------------------------------------------------------------
// Attention (round-10 verbatim — best measured, passing): 32x32x16 MFMAs,
// S transposed, P in registers, zero mask logic, XCD-locality block remap
// (idx = qb*64 + bh -> idx%8 = bh%8 pins each bh's K/V to one XCD's L2).
// grid = B*H*(L/128) = 1024 blocks x 4 waves (each wave: 32 q-rows).
// ---------------------------------------------------------------------------
__global__ __launch_bounds__(256, 4) void attn_kernel(
    const __bf16* __restrict__ Qs, const __bf16* __restrict__ Ks,
    const __bf16* __restrict__ Vp, float* __restrict__ out) {
  const int idx = blockIdx.x;
  const int qb = idx >> 6;        // q-major: 16 q-blocks
  const int bhi = idx & 63;       // bh minor -> idx%8 = h%8 fixed per bh
  const int h = bhi & 7;
  const int b = bhi >> 3;
  const int tid = threadIdx.x;
  const int lane = tid & 63, wave = tid >> 6;
  const int n = lane & 31, hh = lane >> 5;
  const int q0 = qb * 128 + wave * 32;
  const size_t bh = (size_t)(b * H_ + h);

  // Q B-frag: B[k=dh=8*hh+j][n=q]
  const bf16x8 qf = *(const bf16x8*)(Qs + (bh * L_ + q0 + n) * DH_ + 8 * hh);

  const __bf16* Kp = Ks + bh * L_ * DH_ + (size_t)n * DH_ + 8 * hh;
  const __bf16* Vq = Vp + (bh * 64 * 32 + (size_t)n) * 32 + 8 * hh;

  floatx16 acc0, acc1;
#pragma unroll
  for (int r = 0; r < 16; ++r) { acc0[r] = 0.f; acc1[r] = 0.f; }
  const floatx16 zz = acc0;

  auto tile = [&](int t, floatx16& acc) {
    bf16x8 kf = *(const bf16x8*)(Kp + (size_t)t * 32 * DH_);
    const __bf16* vp = Vq + (size_t)t * 1024;
    bf16x8 v0 = *(const bf16x8*)(vp);
    bf16x8 v1 = *(const bf16x8*)(vp + 16);
    floatx16 s = __builtin_amdgcn_mfma_f32_32x32x16_bf16(kf, qf, zz, 0, 0, 0);
    bf16x8 pA, pB;
#pragma unroll
    for (int j = 0; j < 8; ++j) pA[j] = (__bf16)EXP2(s[j]);
#pragma unroll
    for (int j = 0; j < 8; ++j) pB[j] = (__bf16)EXP2(s[8 + j]);
    acc = __builtin_amdgcn_mfma_f32_32x32x16_bf16(v0, pA, acc, 0, 0, 0);
    acc = __builtin_amdgcn_mfma_f32_32x32x16_bf16(v1, pB, acc, 0, 0, 0);
  };

#pragma unroll 1
  for (int t = 0; t < 64; t += 2) {
    tile(t, acc0);
    tile(t + 1, acc1);
  }

  floatx16 acc;
#pragma unroll
  for (int r = 0; r < 16; ++r) acc[r] = acc0[r] + acc1[r];

  // l = row 16 of O^T = acc reg 8 on the hh==0 half; broadcast to hh==1.
  float lmine = acc[8];
  float lother = __shfl_xor(lmine, 32, 64);
  float inv = __builtin_amdgcn_rcpf(hh ? lother : lmine);

  // regs 0-7 are the 8 valid dh rows for this half: dh = (r&3)+8*(r>>2)+4*hh
  float* obase = out + ((size_t)(b * D_ + h * DH_)) * L_ + q0 + n;
#pragma unroll
  for (int r = 0; r < 8; ++r) {
    const int dh = (r & 3) + 8 * (r >> 2) + 4 * hh;
    obase[(size_t)dh * L_] = acc[r] * inv;
  }
}

// ---------------------------------------------------------------------------
extern "C" void kernel_launch(void* const* d_in, const int* in_sizes, int n_in,
                              void* d_out, int out_size, void* d_ws,
                              size_t ws_size, hipStream_t stream) {
  const float* queries = (const float*)d_in[0];  // [B, D, L] fp32
  const int*   mask    = (const int*)d_in[1];    // [B, L] int32
  const float* wmem    = (const float*)d_in[2];  // [2D, D] fp32
  const float* wq      = (const float*)d_in[3];  // [D, D] fp32
  float* out = (float*)d_out;                    // [B, D, L] fp32

  // Workspace: Qs 4 MiB | Ks 4 MiB | Vp 8 MiB.
  const size_t SEG = (size_t)B_ * H_ * L_ * DH_ * sizeof(__bf16);
  __bf16* Qs = (__bf16*)d_ws;
  __bf16* Ks = (__bf16*)((char*)d_ws + SEG);
  __bf16* Vp = (__bf16*)((char*)d_ws + 2 * SEG);

  // Wb (96 KiB) in d_out scratch: wconv writes, proj reads, attn then
  // overwrites ALL of d_out — stream-ordered, race-free.
  __bf16* Wb = (__bf16*)((char*)d_out + (4u << 20));

  wconv_kernel<<<24, 256, 0, stream>>>(wmem, wq, Wb);
  proj_kernel<<<B_ * (L_ / 16), 256, 0, stream>>>(queries, mask, Wb, Qs, Ks, Vp);
  attn_kernel<<<B_ * H_ * (L_ / 128), 256, 0, stream>>>(Qs, Ks, Vp, out);
}

// Round 14
// 118.009 us; speedup vs baseline: 1.0152x; 1.0152x over previous
//
#include <hip/hip_runtime.h>
#include <math.h>

// Problem constants
#define B_  8
#define D_  128
#define L_  2048
#define H_  8
#define DH_ 16

#define LOG2E 1.4426950408889634f

typedef __bf16 bf16x8 __attribute__((ext_vector_type(8)));
typedef float  floatx4 __attribute__((ext_vector_type(4)));
typedef float  floatx16 __attribute__((ext_vector_type(16)));

#if __has_builtin(__builtin_amdgcn_exp2f)
#define EXP2(x) __builtin_amdgcn_exp2f(x)
#else
#define EXP2(x) exp2f(x)
#endif

// ---------------------------------------------------------------------------
// Weight pre-convert (unchanged): fp32 W -> bf16 MFMA frag layout (lane idx =
// col, k = quad*8+j). tiles 0..7 = Q heads (W_q pre-scaled by DH^-0.5*log2e),
// 8..15 = K, 16..23 = V.
// ---------------------------------------------------------------------------
__global__ __launch_bounds__(256) void wconv_kernel(
    const float* __restrict__ wmem, const float* __restrict__ wq,
    __bf16* __restrict__ Wb) {
  const int tile = blockIdx.x;
  const int tid = threadIdx.x;
  const int kc = tid >> 6, lane = tid & 63;
  const int quad = lane >> 4, col = lane & 15;
  const float* src;
  float scale = 1.0f;
  if (tile < 8) {
    src = wq + (tile * 16 + col) * D_;
    scale = 0.25f * LOG2E;  // DH^-0.5 and log2e folded into W_q
  } else if (tile < 16) {
    src = wmem + ((tile - 8) * 16 + col) * D_;
  } else {
    src = wmem + (128 + (tile - 16) * 16 + col) * D_;
  }
  const float* p = src + kc * 32 + quad * 8;
  bf16x8 w;
#pragma unroll
  for (int j = 0; j < 8; ++j) w[j] = (__bf16)(p[j] * scale);
  *(bf16x8*)(Wb + ((size_t)((tile * 4 + kc) * 64) + lane) * 8) = w;
}

// ---------------------------------------------------------------------------
// Projection (round-13 verbatim, passing): LDS-staged C-tiles, coalesced
// 16B/lane dumps.
//   Qs [B,H,L,DH] natural.
//   Ks [B,H,L,DH], rows tau-permuted (key bits 2<->3 swapped).
//   Vp [bh][tile=l>>5][row 0..16][kk=l&31]; rows 0-15 = V^T*mask,
//      row 16 = mask (l-sum row), rows 17-31 unwritten (harmless garbage).
// ---------------------------------------------------------------------------
__global__ __launch_bounds__(256) void proj_kernel(
    const float* __restrict__ qin, const int* __restrict__ mask,
    const __bf16* __restrict__ Wb, __bf16* __restrict__ Qs,
    __bf16* __restrict__ Ks, __bf16* __restrict__ Vp) {
  __shared__ float xl[16][132];        // row stride >= 128 (D)!
  __shared__ __bf16 qbuf[8][16][16];   // [head][l][dh]
  __shared__ __bf16 kbuf[8][16][16];   // [head][tau-row][dh]
  __shared__ __bf16 vbuf[8][17][16];   // [head][dh-row (16=mask)][key-in-16]
  const int b = blockIdx.x >> 7;
  const int l0 = (blockIdx.x & 127) * 16;
  const int tid = threadIdx.x;

#pragma unroll
  for (int i = 0; i < 2; ++i) {
    int idx = i * 256 + tid;
    int d = idx >> 2;
    int l4 = (idx & 3) * 4;
    const float4 v = *(const float4*)&qin[(b * D_ + d) * L_ + l0 + l4];
    xl[l4 + 0][d] = v.x;
    xl[l4 + 1][d] = v.y;
    xl[l4 + 2][d] = v.z;
    xl[l4 + 3][d] = v.w;
  }
  if (tid < 128) {
    const int hh = tid >> 4, c = tid & 15;
    vbuf[hh][16][c] = (__bf16)(float)mask[b * L_ + l0 + c];
  }
  __syncthreads();

  const int lane = tid & 63, wave = tid >> 6;
  const int quad = lane >> 4, col = lane & 15;

  bf16x8 af[4];
#pragma unroll
  for (int kc = 0; kc < 4; ++kc) {
    const float* s = &xl[col][kc * 32 + quad * 8];
#pragma unroll
    for (int j = 0; j < 8; ++j) af[kc][j] = (__bf16)s[j];
  }

  const int quadK = ((quad & 1) << 1) | (quad >> 1);   // tau: swap bits 2,3
  const float mvv = (float)mask[b * L_ + l0 + col];    // V column mask

#pragma unroll
  for (int tt = 0; tt < 6; ++tt) {
    const int tile = wave * 6 + tt;
    floatx4 acc = {0.f, 0.f, 0.f, 0.f};
    const bool isV = (tile >= 16);
#pragma unroll
    for (int kc = 0; kc < 4; ++kc) {
      bf16x8 wf =
          *(const bf16x8*)(Wb + ((size_t)((tile * 4 + kc) * 64) + lane) * 8);
      acc = isV ? __builtin_amdgcn_mfma_f32_16x16x32_bf16(wf, af[kc], acc, 0, 0, 0)
                : __builtin_amdgcn_mfma_f32_16x16x32_bf16(af[kc], wf, acc, 0, 0, 0);
    }
    if (tile < 8) {
#pragma unroll
      for (int r = 0; r < 4; ++r) qbuf[tile][quad * 4 + r][col] = (__bf16)acc[r];
    } else if (tile < 16) {
#pragma unroll
      for (int r = 0; r < 4; ++r)
        kbuf[tile - 8][quadK * 4 + r][col] = (__bf16)acc[r];
    } else {
#pragma unroll
      for (int r = 0; r < 4; ++r)
        vbuf[tile - 16][quad * 4 + r][col] = (__bf16)(acc[r] * mvv);
    }
  }
  __syncthreads();

  {
    const int h = tid >> 5, sub = tid & 31;
    const size_t base = ((size_t)(b * H_ + h) * L_ + l0) * DH_;
    bf16x8 q8 = *(const bf16x8*)&qbuf[h][sub >> 1][(sub & 1) * 8];
    *(bf16x8*)(Qs + base + sub * 8) = q8;
    bf16x8 k8 = *(const bf16x8*)&kbuf[h][sub >> 1][(sub & 1) * 8];
    *(bf16x8*)(Ks + base + sub * 8) = k8;
  }
  if (tid < 136) {
    const int h = tid / 17, row = tid - h * 17;
    const size_t off =
        ((size_t)((b * H_ + h) * 64 + (l0 >> 5)) * 32 + row) * 32 + (l0 & 16);
    bf16x8 a = *(const bf16x8*)&vbuf[h][row][0];
    bf16x8 c = *(const bf16x8*)&vbuf[h][row][8];
    *(bf16x8*)(Vp + off) = a;
    *(bf16x8*)(Vp + off + 8) = c;
  }
}

// ---------------------------------------------------------------------------
// Attention v11: round-10 register dataflow + m97-style cooperative LDS
// staging with barrier-pinned one-tile prefetch.
// Per tile (3 KB: K 1KB + V 2KB incl. unread garbage rows 17-31): threads
// 0-191 load 16B each. Body: gload(t+1) -> compute(t from LDS buf[t&1])
// -> dswrite(t+1 -> buf[(t+1)&1]) -> __syncthreads(). The barrier makes the
// prefetch distance compiler-proof; global latency is covered by compute(t);
// each K/V line now fetched ONCE per block (was 4x, once per wave).
// Hazards: compute(t) reads buf[t&1]; dswrite(t+1) writes the other buf;
// writes to buf[t&1] (for t+2) occur only after the barrier that follows
// compute(t). ds_read chain ~120 cyc replaces ~300-900 cyc global chain.
// grid = B*H*(L/128) = 1024 blocks x 4 waves; XCD swizzle idx = qb*64+bh.
// ---------------------------------------------------------------------------
__global__ __launch_bounds__(256, 4) void attn_kernel(
    const __bf16* __restrict__ Qs, const __bf16* __restrict__ Ks,
    const __bf16* __restrict__ Vp, float* __restrict__ out) {
  __shared__ __bf16 kls[2][512];   // [buf][tile image] 1 KB
  __shared__ __bf16 vls[2][1024];  // [buf][tile image] 2 KB
  const int idx = blockIdx.x;
  const int qb = idx >> 6;        // q-major: 16 q-blocks
  const int bhi = idx & 63;       // bh minor -> idx%8 = h%8 (XCD pin)
  const int h = bhi & 7;
  const int b = bhi >> 3;
  const int tid = threadIdx.x;
  const int lane = tid & 63, wave = tid >> 6;
  const int n = lane & 31, hh = lane >> 5;
  const int q0 = qb * 128 + wave * 32;
  const size_t bh = (size_t)(b * H_ + h);

  // Q B-frag: B[k=dh=8*hh+j][n=q]
  const bf16x8 qf = *(const bf16x8*)(Qs + (bh * L_ + q0 + n) * DH_ + 8 * hh);

  const __bf16* Kg = Ks + bh * L_ * DH_;   // tile t at +t*512 (1 KB contig)
  const __bf16* Vg = Vp + bh * 65536;      // tile t at +t*1024 (2 KB contig)

  floatx16 acc0, acc1;
#pragma unroll
  for (int r = 0; r < 16; ++r) { acc0[r] = 0.f; acc1[r] = 0.f; }
  const floatx16 zz = acc0;

  // Cooperative staging: thread sid<64 -> K elems [sid*8,+8); sid in
  // [64,192) -> V elems [(sid-64)*8,+8); sid>=192 idle (wave 3 computes only).
  bf16x8 streg = {};
  auto gload = [&](int t) {
    if (tid < 64)
      streg = *(const bf16x8*)(Kg + (size_t)t * 512 + tid * 8);
    else if (tid < 192)
      streg = *(const bf16x8*)(Vg + (size_t)t * 1024 + (tid - 64) * 8);
  };
  auto dswrite = [&](int t) {
    const int bi = t & 1;
    if (tid < 64)
      *(bf16x8*)&kls[bi][tid * 8] = streg;
    else if (tid < 192)
      *(bf16x8*)&vls[bi][(tid - 64) * 8] = streg;
  };

  auto compute = [&](int t, floatx16& acc) {
    const int bi = t & 1;
    bf16x8 kf = *(const bf16x8*)&kls[bi][n * 16 + 8 * hh];
    bf16x8 v0 = *(const bf16x8*)&vls[bi][n * 32 + 8 * hh];
    bf16x8 v1 = *(const bf16x8*)&vls[bi][n * 32 + 16 + 8 * hh];
    floatx16 s = __builtin_amdgcn_mfma_f32_32x32x16_bf16(kf, qf, zz, 0, 0, 0);
    bf16x8 pA, pB;
#pragma unroll
    for (int j = 0; j < 8; ++j) pA[j] = (__bf16)EXP2(s[j]);
#pragma unroll
    for (int j = 0; j < 8; ++j) pB[j] = (__bf16)EXP2(s[8 + j]);
    acc = __builtin_amdgcn_mfma_f32_32x32x16_bf16(v0, pA, acc, 0, 0, 0);
    acc = __builtin_amdgcn_mfma_f32_32x32x16_bf16(v1, pB, acc, 0, 0, 0);
  };

  // Preamble: stage tile 0 into buf0.
  gload(0);
  dswrite(0);
  __syncthreads();

#pragma unroll 1
  for (int t = 0; t < 62; t += 2) {
    gload(t + 1);
    compute(t, acc0);        // buf0
    dswrite(t + 1);          // -> buf1
    __syncthreads();
    gload(t + 2);
    compute(t + 1, acc1);    // buf1
    dswrite(t + 2);          // -> buf0 (safe: post-barrier of compute(t))
    __syncthreads();
  }
  // Loop staged tiles 61 (buf1) and 62 (buf0). Finish 62, stage 63, do 63.
  gload(63);
  compute(62, acc0);         // buf0
  dswrite(63);               // -> buf1
  __syncthreads();
  compute(63, acc1);         // buf1

  floatx16 acc;
#pragma unroll
  for (int r = 0; r < 16; ++r) acc[r] = acc0[r] + acc1[r];

  // l = row 16 of O^T = acc reg 8 on the hh==0 half; broadcast to hh==1.
  float lmine = acc[8];
  float lother = __shfl_xor(lmine, 32, 64);
  float inv = __builtin_amdgcn_rcpf(hh ? lother : lmine);

  // regs 0-7 are the 8 valid dh rows for this half: dh = (r&3)+8*(r>>2)+4*hh
  float* obase = out + ((size_t)(b * D_ + h * DH_)) * L_ + q0 + n;
#pragma unroll
  for (int r = 0; r < 8; ++r) {
    const int dh = (r & 3) + 8 * (r >> 2) + 4 * hh;
    obase[(size_t)dh * L_] = acc[r] * inv;
  }
}

// ---------------------------------------------------------------------------
extern "C" void kernel_launch(void* const* d_in, const int* in_sizes, int n_in,
                              void* d_out, int out_size, void* d_ws,
                              size_t ws_size, hipStream_t stream) {
  const float* queries = (const float*)d_in[0];  // [B, D, L] fp32
  const int*   mask    = (const int*)d_in[1];    // [B, L] int32
  const float* wmem    = (const float*)d_in[2];  // [2D, D] fp32
  const float* wq      = (const float*)d_in[3];  // [D, D] fp32
  float* out = (float*)d_out;                    // [B, D, L] fp32

  // Workspace: Qs 4 MiB | Ks 4 MiB | Vp 8 MiB.
  const size_t SEG = (size_t)B_ * H_ * L_ * DH_ * sizeof(__bf16);
  __bf16* Qs = (__bf16*)d_ws;
  __bf16* Ks = (__bf16*)((char*)d_ws + SEG);
  __bf16* Vp = (__bf16*)((char*)d_ws + 2 * SEG);

  // Wb (96 KiB) in d_out scratch: wconv writes, proj reads, attn then
  // overwrites ALL of d_out — stream-ordered, race-free.
  __bf16* Wb = (__bf16*)((char*)d_out + (4u << 20));

  wconv_kernel<<<24, 256, 0, stream>>>(wmem, wq, Wb);
  proj_kernel<<<B_ * (L_ / 16), 256, 0, stream>>>(queries, mask, Wb, Qs, Ks, Vp);
  attn_kernel<<<B_ * H_ * (L_ / 128), 256, 0, stream>>>(Qs, Ks, Vp, out);
}